// Round 1
// baseline (509.903 us; speedup 1.0000x reference)
//
#include <hip/hip_runtime.h>

#define NROWS 8192
#define NCOLS 8192
#define LD    8193          // matching_scores row stride (8193x8193 input)
#define NBINS 64
#define KCORR 2048
#define MAXC  8192
#define NCOPY 64            // sub-histogram copies (one per lane id)
#define CSTRIDE 65          // +1 pad to spread copies across banks

// inner value EXACTLY as the reference: p = ref_i * src_j; v = exp(m) * p
__device__ __forceinline__ float inner_val(float m, float rr, float sc) {
    float p = rr * sc;
    return expf(m) * p;
}

// Fill outputs with the invalid-slot values; zero the global histogram.
__global__ void init_kernel(float* __restrict__ out, unsigned* __restrict__ hist) {
    int i = blockIdx.x * blockDim.x + threadIdx.x;
    if (i < 2 * MAXC)       out[i] = -1.0f;   // ref/src index fill
    else if (i < 3 * MAXC)  out[i] = 0.0f;    // score fill
    if (i < NBINS) hist[i] = 0u;
}

// One block per row: bin every element by "first threshold it exceeds",
// accumulate into 64 lane-private sub-histograms (bank-padded, low-contention
// LDS atomics), reduce to global hist + per-row hist.
__global__ __launch_bounds__(256) void hist_kernel(
    const float* __restrict__ ms, const float* __restrict__ refs,
    const float* __restrict__ srcs, unsigned* __restrict__ hist,
    unsigned* __restrict__ rowhist, int use_rowhist)
{
    __shared__ float t[NBINS];
    __shared__ unsigned sub[NCOPY * CSTRIDE];
    int tid = threadIdx.x;
    if (tid == 0) {  // replicate the reference's float32 threshold sequence
        float tv = 0.5f;
        for (int n = 0; n < NBINS; ++n) { t[n] = tv; tv = tv - 0.01f; }
    }
    for (int i = tid; i < NCOPY * CSTRIDE; i += 256) sub[i] = 0u;
    __syncthreads();

    int row = blockIdx.x;
    int lane = tid & 63;
    float rr = refs[row];
    const float* mrow = ms + (size_t)row * LD;
    unsigned* mysub = sub + lane * CSTRIDE;

    for (int c = tid; c < NCOLS; c += 256) {
        float v = inner_val(mrow[c], rr, srcs[c]);
        // smallest n with v > t[n]  (t descending -> predicate monotone)
        int lo = 0, hi = NBINS;
        while (lo < hi) { int mid = (lo + hi) >> 1; if (v > t[mid]) hi = mid; else lo = mid + 1; }
        int b = (lo < NBINS) ? lo : (NBINS - 1);
        atomicAdd(&mysub[b], 1u);
    }
    __syncthreads();
    if (tid < NBINS) {
        unsigned s = 0;
        for (int c = 0; c < NCOPY; ++c) s += sub[c * CSTRIDE + tid];
        if (use_rowhist) rowhist[(size_t)row * NBINS + tid] = s;
        if (s) atomicAdd(&hist[tid], s);
    }
}

// Replay the while-loop on the 64-bin cumulative histogram.
__global__ void thres_kernel(const unsigned* __restrict__ hist,
                             float* __restrict__ thres, unsigned* __restrict__ nstar) {
    if (threadIdx.x == 0) {
        float tv = 0.5f;
        unsigned cum = 0;
        int nsel = NBINS - 1;
        for (int n = 0; n < NBINS; ++n) {
            cum += hist[n];
            if (cum >= KCORR) { nsel = n; break; }
            tv = tv - 0.01f;
        }
        *thres = tv;
        *nstar = (unsigned)nsel;
    }
}

// Per-row match count from the per-row histograms (no matrix re-read).
__global__ void rowcnt_kernel(const unsigned* __restrict__ rowhist,
                              const unsigned* __restrict__ nstar,
                              unsigned* __restrict__ rowcnt) {
    int r = blockIdx.x * blockDim.x + threadIdx.x;
    if (r < NROWS) {
        int ns = (int)*nstar;
        const unsigned* rh = rowhist + (size_t)r * NBINS;
        unsigned s = 0;
        for (int b = 0; b <= ns; ++b) s += rh[b];
        rowcnt[r] = s;
    }
}

// Fallback (ws too small for rowhist): recount by full pass.
__global__ __launch_bounds__(256) void count_kernel(
    const float* __restrict__ ms, const float* __restrict__ refs,
    const float* __restrict__ srcs, const float* __restrict__ thresp,
    unsigned* __restrict__ rowcnt)
{
    __shared__ unsigned tot;
    if (threadIdx.x == 0) tot = 0;
    __syncthreads();
    int row = blockIdx.x;
    float rr = refs[row];
    float th = *thresp;
    const float* mrow = ms + (size_t)row * LD;
    unsigned cnt = 0;
    for (int c = threadIdx.x; c < NCOLS; c += 256)
        cnt += (inner_val(mrow[c], rr, srcs[c]) > th) ? 1u : 0u;
    atomicAdd(&tot, cnt);
    __syncthreads();
    if (threadIdx.x == 0) rowcnt[row] = tot;
}

// Exclusive prefix over 8192 row counts (single block, 8 rows/thread).
__global__ __launch_bounds__(1024) void scan_kernel(
    const unsigned* __restrict__ rowcnt, unsigned* __restrict__ rowoff,
    unsigned* __restrict__ total)
{
    __shared__ unsigned ssum[1024];
    int tid = threadIdx.x;
    int r0 = tid * 8;
    unsigned c[8], s = 0;
    for (int k = 0; k < 8; ++k) { c[k] = rowcnt[r0 + k]; s += c[k]; }
    ssum[tid] = s;
    __syncthreads();
    for (int off = 1; off < 1024; off <<= 1) {
        unsigned v = (tid >= off) ? ssum[tid - off] : 0u;
        __syncthreads();
        ssum[tid] += v;
        __syncthreads();
    }
    unsigned excl = ssum[tid] - s;
    for (int k = 0; k < 8; ++k) { rowoff[r0 + k] = excl; excl += c[k]; }
    if (tid == 1023) { rowoff[NROWS] = excl; *total = excl; }
}

// One wave per row: ordered ballot compaction. Empty rows read nothing;
// non-empty rows early-exit once their matches are found.
__global__ __launch_bounds__(256) void write_kernel(
    const float* __restrict__ ms, const float* __restrict__ refs,
    const float* __restrict__ srcs, const float* __restrict__ thresp,
    const unsigned* __restrict__ rowoff, float* __restrict__ out)
{
    int wave = threadIdx.x >> 6, lane = threadIdx.x & 63;
    int row = blockIdx.x * 4 + wave;
    unsigned base = rowoff[row], next = rowoff[row + 1];
    if (base == next || base >= MAXC) return;  // wave-uniform
    float th = *thresp;
    float rr = refs[row];
    const float* mrow = ms + (size_t)row * LD;
    float* outR = out;
    float* outC = out + MAXC;
    float* outS = out + 2 * MAXC;
    unsigned running = base;
    for (int c0 = 0; c0 < NCOLS; c0 += 64) {
        int col = c0 + lane;
        float v = inner_val(mrow[col], rr, srcs[col]);
        bool pred = v > th;
        unsigned long long mk = __ballot(pred);
        if (pred) {
            unsigned pos = running + (unsigned)__popcll(mk & ((1ull << lane) - 1ull));
            if (pos < MAXC) {
                outR[pos] = (float)row;
                outC[pos] = (float)col;
                outS[pos] = v;
            }
        }
        running += (unsigned)__popcll(mk);
        if (running >= next || running >= MAXC) break;
    }
}

extern "C" void kernel_launch(void* const* d_in, const int* in_sizes, int n_in,
                              void* d_out, int out_size, void* d_ws, size_t ws_size,
                              hipStream_t stream) {
    const float* ms  = (const float*)d_in[0];  // 8193x8193
    const float* ref = (const float*)d_in[1];  // 8192
    const float* src = (const float*)d_in[2];  // 8192
    float* out = (float*)d_out;                // [refIdx | srcIdx | scores] as f32

    char* w = (char*)d_ws;
    unsigned* hist   = (unsigned*)(w);                    // 64 u32
    float*    thres  = (float*)(w + 256);
    unsigned* nstar  = (unsigned*)(w + 260);
    unsigned* total  = (unsigned*)(w + 264);
    unsigned* rowcnt = (unsigned*)(w + 512);              // 8192 u32
    unsigned* rowoff = (unsigned*)(w + 512 + NROWS * 4);  // 8193 u32
    size_t rh_off = 512 + (size_t)NROWS * 4 + (size_t)(NROWS + 1) * 4;
    rh_off = (rh_off + 255) & ~(size_t)255;
    unsigned* rowhist = (unsigned*)(w + rh_off);          // 8192*64 u32 = 2 MB
    int use_rowhist = (ws_size >= rh_off + (size_t)NROWS * NBINS * 4) ? 1 : 0;

    init_kernel<<<96, 256, 0, stream>>>(out, hist);
    hist_kernel<<<NROWS, 256, 0, stream>>>(ms, ref, src, hist, rowhist, use_rowhist);
    thres_kernel<<<1, 64, 0, stream>>>(hist, thres, nstar);
    if (use_rowhist)
        rowcnt_kernel<<<NROWS / 256, 256, 0, stream>>>(rowhist, nstar, rowcnt);
    else
        count_kernel<<<NROWS, 256, 0, stream>>>(ms, ref, src, thres, rowcnt);
    scan_kernel<<<1, 1024, 0, stream>>>(rowcnt, rowoff, total);
    write_kernel<<<NROWS / 4, 256, 0, stream>>>(ms, ref, src, thres, rowoff, out);
}